// Round 7
// baseline (233.766 us; speedup 1.0000x reference)
//
#include <hip/hip_runtime.h>

typedef __attribute__((ext_vector_type(8)))  short bf16x8;   // MFMA A/B frag (4 VGPRs)
typedef __attribute__((ext_vector_type(4)))  float f32x4;    // 16x16 C/D frag
typedef __attribute__((ext_vector_type(16))) float f32x16;   // 32x32 C/D frag
typedef __attribute__((ext_vector_type(4)))  unsigned u32x4;

#define Nx 2048
#define CTXx 2049
#define KCAP 2112          // 33 tiles of 64; pad keys stay poison (finite bf16) & masked
#define QSCALE 0.18033688f // 0.125 * log2(e): softmax computed as 2^(S*log2e) = e^S

__device__ __forceinline__ short f2bs(float x){   // float -> bf16 bits (RNE)
    unsigned u = __builtin_bit_cast(unsigned, x);
    u = (u + 0x7fffu + ((u >> 16) & 1u)) >> 16;
    return (short)u;
}
__device__ __forceinline__ float us2f(unsigned short u){
    union { unsigned i; float f; } c; c.i = ((unsigned)u) << 16; return c.f;
}
// truncating pack: (hi16 of b)<<16 | (hi16 of a) — 1 v_perm_b32
__device__ __forceinline__ unsigned pack_trunc(float a, float b){
    return __builtin_amdgcn_perm(__builtin_bit_cast(unsigned, b),
                                 __builtin_bit_cast(unsigned, a), 0x07060302u);
}

// ---------------- fused LN1 (blocks 0..2047) + weight prep (2048..2192) ----------------
__global__ void __launch_bounds__(256) ln1_prep_kernel(const float* __restrict__ x,
                                                       const float* __restrict__ g,
                                                       short* __restrict__ xnb,
                                                       const float* __restrict__ Wq,
                                                       const float* __restrict__ Wkv,
                                                       const float* __restrict__ Wout,
                                                       const float* __restrict__ nkv,
                                                       short* __restrict__ WcatT,
                                                       short* __restrict__ WoutT,
                                                       short* __restrict__ kb,
                                                       short* __restrict__ vbt){
    __shared__ float ls[64][65];
    int t = threadIdx.x;
    if (blockIdx.x < 2048){    // ---- LN1: wave per row, fp32 -> bf16 ----
        int w = t >> 6, lane = t & 63;
        size_t row = (size_t)blockIdx.x * 4 + w;
        const float* xr = x + row * 512 + lane * 8;
        float4 a = *(const float4*)xr;
        float4 b = *(const float4*)(xr + 4);
        float s = a.x + a.y + a.z + a.w + b.x + b.y + b.z + b.w;
        float q = a.x*a.x + a.y*a.y + a.z*a.z + a.w*a.w
                + b.x*b.x + b.y*b.y + b.z*b.z + b.w*b.w;
        #pragma unroll
        for (int m = 1; m < 64; m <<= 1){ s += __shfl_xor(s, m, 64); q += __shfl_xor(q, m, 64); }
        float mu  = s * (1.f / 512.f);
        float var = fmaxf(q * (1.f / 512.f) - mu * mu, 0.f);
        float r   = rsqrtf(var + 1e-5f);
        const float* gr = g + lane * 8;
        float4 g0 = *(const float4*)gr;
        float4 g1 = *(const float4*)(gr + 4);
        bf16x8 o;
        o[0] = f2bs((a.x - mu) * r * g0.x); o[1] = f2bs((a.y - mu) * r * g0.y);
        o[2] = f2bs((a.z - mu) * r * g0.z); o[3] = f2bs((a.w - mu) * r * g0.w);
        o[4] = f2bs((b.x - mu) * r * g1.x); o[5] = f2bs((b.y - mu) * r * g1.y);
        o[6] = f2bs((b.z - mu) * r * g1.z); o[7] = f2bs((b.w - mu) * r * g1.w);
        *(bf16x8*)(xnb + row * 512 + lane * 8) = o;
        return;
    }
    int bid = blockIdx.x - 2048;
    if (bid == 144){   // null K/V row (key 0, all batches)
        int b = t >> 6, d = t & 63;
        kb[((size_t)b * KCAP) * 64 + d] = f2bs(nkv[d]);
        vbt[((size_t)b * 64 + d) * KCAP + 0] = f2bs(nkv[64 + d]);
        return;
    }
    // ---- LDS-tiled transpose: 0..79 WcatT (640x512), 80..143 WoutT (512x512) ----
    bool isOut = (bid >= 80);
    int b2 = isOut ? bid - 80 : bid;
    int ntile = isOut ? (b2 & 7) : (b2 % 10);
    int ktile = isOut ? (b2 >> 3) : (b2 / 10);
    int n0 = ntile * 64, k0 = ktile * 64;
    #pragma unroll
    for (int rr = 0; rr < 64; rr += 16){   // coalesced float4 reads of W[k][n]
        int r = rr + (t >> 4), c = (t & 15) * 4;
        float4 v;
        if (isOut)            v = *(const float4*)(Wout + (size_t)(k0 + r) * 512 + n0 + c);
        else if (n0 < 512)    v = *(const float4*)(Wq   + (size_t)(k0 + r) * 512 + n0 + c);
        else                  v = *(const float4*)(Wkv  + (size_t)(k0 + r) * 128 + (n0 - 512) + c);
        ls[c + 0][r] = v.x; ls[c + 1][r] = v.y; ls[c + 2][r] = v.z; ls[c + 3][r] = v.w;
    }
    __syncthreads();
    int rn = t >> 2, kc = (t & 3) * 16;    // coalesced 32B bf16 writes of W^T[n][k]
    short tmp[16];
    #pragma unroll
    for (int j = 0; j < 16; j++) tmp[j] = f2bs(ls[rn][kc + j]);
    short* dst = (isOut ? WoutT : WcatT) + (size_t)(n0 + rn) * 512 + k0 + kc;
    *(int4*)dst       = *(int4*)&tmp[0];
    *(int4*)(dst + 8) = *(int4*)&tmp[8];
}

// ---------------- LN2: fp32 in -> fp32 out, wave per row ----------------
__global__ void __launch_bounds__(256) ln2_kernel(const float* __restrict__ z,
                                                  const float* __restrict__ g,
                                                  float* __restrict__ out){
    int w = threadIdx.x >> 6, lane = threadIdx.x & 63;
    size_t row = (size_t)blockIdx.x * 4 + w;
    const float* xr = z + row * 512 + lane * 8;
    float4 a = *(const float4*)xr;
    float4 b = *(const float4*)(xr + 4);
    float s = a.x + a.y + a.z + a.w + b.x + b.y + b.z + b.w;
    float q = a.x*a.x + a.y*a.y + a.z*a.z + a.w*a.w
            + b.x*b.x + b.y*b.y + b.z*b.z + b.w*b.w;
    #pragma unroll
    for (int m = 1; m < 64; m <<= 1){ s += __shfl_xor(s, m, 64); q += __shfl_xor(q, m, 64); }
    float mu  = s * (1.f / 512.f);
    float var = fmaxf(q * (1.f / 512.f) - mu * mu, 0.f);
    float r   = rsqrtf(var + 1e-5f);
    const float* gr = g + lane * 8;
    float4 g0 = *(const float4*)gr;
    float4 g1 = *(const float4*)(gr + 4);
    float4 o0, o1;
    o0.x = (a.x - mu) * r * g0.x; o0.y = (a.y - mu) * r * g0.y;
    o0.z = (a.z - mu) * r * g0.z; o0.w = (a.w - mu) * r * g0.w;
    o1.x = (b.x - mu) * r * g1.x; o1.y = (b.y - mu) * r * g1.y;
    o1.z = (b.z - mu) * r * g1.z; o1.w = (b.w - mu) * r * g1.w;
    float* op = out + row * 512 + lane * 8;
    *(float4*)op = o0; *(float4*)(op + 4) = o1;
}

// ---------------- MFMA GEMM: 128x128 tile, BK=64, LDS dbuf + reg prefetch ----------------
// MODE 0: C = xn @ [Wq|Wkv] (N=640): q-scale(incl log2e) + K scatter + V^T scatter (bf16)
// MODE 1: C = ob @ Wout (N=512): fp32 out
template<int MODE>
__global__ void __launch_bounds__(256, 2) gemm_mfma(const short* __restrict__ A,
                                                    const short* __restrict__ BwT,
                                                    short* __restrict__ qb,
                                                    short* __restrict__ kb,
                                                    short* __restrict__ vbt,
                                                    float* __restrict__ C){
    __shared__ short As[2][128][72];   // [buf][m][k]
    __shared__ short Bs[2][128][72];   // [buf][n][k]
    int t = threadIdx.x;
    int lane = t & 63, w = t >> 6;
    int l16 = lane & 15, quad = lane >> 4;
    int wm = w & 1, wn = w >> 1;
    int row0 = blockIdx.y * 128, col0 = blockIdx.x * 128;
    f32x4 acc[4][4];
    #pragma unroll
    for (int i = 0; i < 4; i++)
        #pragma unroll
        for (int j = 0; j < 4; j++) acc[i][j] = (f32x4){0.f, 0.f, 0.f, 0.f};
    int ar = t >> 1, ak = (t & 1) * 32;
    const short* ap = A   + (size_t)(row0 + ar) * 512 + ak;
    const short* bp = BwT + (size_t)(col0 + ar) * 512 + ak;
    int4 a0 = *(const int4*)(ap);      int4 a1 = *(const int4*)(ap + 8);
    int4 a2 = *(const int4*)(ap + 16); int4 a3 = *(const int4*)(ap + 24);
    int4 b0 = *(const int4*)(bp);      int4 b1 = *(const int4*)(bp + 8);
    int4 b2 = *(const int4*)(bp + 16); int4 b3 = *(const int4*)(bp + 24);
    int p = 0;
    for (int k0 = 0; k0 < 512; k0 += 64){
        *(int4*)&As[p][ar][ak]      = a0;
        *(int4*)&As[p][ar][ak + 8]  = a1;
        *(int4*)&As[p][ar][ak + 16] = a2;
        *(int4*)&As[p][ar][ak + 24] = a3;
        *(int4*)&Bs[p][ar][ak]      = b0;
        *(int4*)&Bs[p][ar][ak + 8]  = b1;
        *(int4*)&Bs[p][ar][ak + 16] = b2;
        *(int4*)&Bs[p][ar][ak + 24] = b3;
        __syncthreads();
        int kn = k0 + 64;
        if (kn < 512){   // prefetch next k-slab while computing this one
            a0 = *(const int4*)(ap + kn);      a1 = *(const int4*)(ap + kn + 8);
            a2 = *(const int4*)(ap + kn + 16); a3 = *(const int4*)(ap + kn + 24);
            b0 = *(const int4*)(bp + kn);      b1 = *(const int4*)(bp + kn + 8);
            b2 = *(const int4*)(bp + kn + 16); b3 = *(const int4*)(bp + kn + 24);
        }
        #pragma unroll
        for (int ks = 0; ks < 2; ks++){
            bf16x8 af[4], bfr[4];
            #pragma unroll
            for (int mt = 0; mt < 4; mt++)
                af[mt] = *(const bf16x8*)&As[p][wm * 64 + mt * 16 + l16][ks * 32 + quad * 8];
            #pragma unroll
            for (int nt = 0; nt < 4; nt++)
                bfr[nt] = *(const bf16x8*)&Bs[p][wn * 64 + nt * 16 + l16][ks * 32 + quad * 8];
            #pragma unroll
            for (int mt = 0; mt < 4; mt++)
                #pragma unroll
                for (int nt = 0; nt < 4; nt++)
                    acc[mt][nt] = __builtin_amdgcn_mfma_f32_16x16x32_bf16(af[mt], bfr[nt], acc[mt][nt], 0, 0, 0);
        }
        p ^= 1;
    }
    #pragma unroll
    for (int mt = 0; mt < 4; mt++)
        #pragma unroll
        for (int nt = 0; nt < 4; nt++)
            #pragma unroll
            for (int r = 0; r < 4; r++){
                int row = row0 + wm * 64 + mt * 16 + quad * 4 + r;
                int col = col0 + wn * 64 + nt * 16 + l16;
                float v = acc[mt][nt][r];
                if (MODE == 0){
                    int bb = row >> 11, ii = row & 2047;
                    if (col < 512){
                        qb[(size_t)row * 512 + col] = f2bs(v * QSCALE);
                    } else if (col < 576){
                        kb[((size_t)bb * KCAP + ii + 1) * 64 + (col - 512)] = f2bs(v);
                    } else {
                        vbt[((size_t)bb * 64 + (col - 576)) * KCAP + ii + 1] = f2bs(v);
                    }
                } else {
                    C[(size_t)row * 512 + col] = v;
                }
            }
}

// ---------------- MFMA attention v4: key-split halves, K+V LDS dbuf, 1 barrier/tile ----------------
// Grid (128 row-tiles, 4 batches, 2 key-halves). Block = 16 q-rows x 8 heads; wave = 2 heads.
// S^T = K.Q^T (A=K from LDS, B=Q): exp/mask/pack in registers; P->A via bit2<->bit3-swapped V.
// L via mfma(P, ones) -> same reg index as oacc rows. Writes UNNORMALIZED bf16 partial O + fp32 L.
__global__ void __launch_bounds__(256, 4) attn_kernel(const short* __restrict__ qb,
                                                      const short* __restrict__ kb,
                                                      const short* __restrict__ vbt,
                                                      const int* __restrict__ mask,
                                                      short* __restrict__ obp,
                                                      float* __restrict__ lp){
    __shared__ short Ks[2][64][72];   // [buf][key][d]
    __shared__ short Vt[2][64][72];   // [buf][d][key], key cols bit2<->bit3 swapped
    int t = threadIdx.x;
    int lane = t & 63, w = t >> 6;
    int n32 = lane & 31, hb = lane >> 5;
    int b = blockIdx.y, i0 = blockIdx.x * 16, half = blockIdx.z;
    int jt0 = half ? 17 : 0, jt1 = half ? 33 : 17;
    int head = 2 * w + (n32 >> 4), row = i0 + (n32 & 15);
    // Q frags (B-operand): B[k=8hb+j][n=n32]
    bf16x8 qf[4];
    {
        const short* qp = qb + ((size_t)(b * Nx + row)) * 512 + head * 64 + hb * 8;
        #pragma unroll
        for (int ks = 0; ks < 4; ks++) qf[ks] = *(const bf16x8*)(qp + ks * 16);
    }
    bf16x8 ones;
    #pragma unroll
    for (int j = 0; j < 8; j++) ones[j] = (short)0x3F80;   // bf16 1.0
    f32x16 oacc[2], lacc;
    #pragma unroll
    for (int j = 0; j < 16; j++){ oacc[0][j] = 0.f; oacc[1][j] = 0.f; lacc[j] = 0.f; }

    int skey = t >> 2, sd = (t & 3) * 16;   // K staging: 64 keys x 64 d
    int vd   = t >> 2, vk = (t & 3) * 16;   // V staging: 64 d x 64 keys
    const short* kgp = kb  + (size_t)b * KCAP * 64 + skey * 64 + sd;
    const short* vgp = vbt + ((size_t)b * 64 + vd) * KCAP + vk;
    const int* mrow = mask + b * Nx;

    // prefetch first tile of this half
    int j0 = jt0 * 64;
    int4 pk0 = *(const int4*)(kgp + (size_t)j0 * 64);
    int4 pk1 = *(const int4*)(kgp + (size_t)j0 * 64 + 8);
    int4 pv0 = *(const int4*)(vgp + j0);
    int4 pv1 = *(const int4*)(vgp + j0 + 8);
    int jg0 = j0 + lane;
    int mok = (jg0 == 0) ? 1 : ((jg0 < CTXx) ? mrow[jg0 - 1] : 0);

    int p = 0;
    for (int jt = jt0; jt < jt1; ++jt){
        *(int4*)&Ks[p][skey][sd]     = pk0;
        *(int4*)&Ks[p][skey][sd + 8] = pk1;
        // bit2<->bit3 key permutation == swap middle dwords of the two int4s
        *(int4*)&Vt[p][vd][vk]       = make_int4(pv0.x, pv0.y, pv1.x, pv1.y);
        *(int4*)&Vt[p][vd][vk + 8]   = make_int4(pv0.z, pv0.w, pv1.z, pv1.w);
        unsigned long long bal = __ballot(mok != 0);
        __syncthreads();
        int jn = (jt + 1) * 64;
        if (jt + 1 < jt1){   // prefetch next tile into regs (hides under compute)
            pk0 = *(const int4*)(kgp + (size_t)jn * 64);
            pk1 = *(const int4*)(kgp + (size_t)jn * 64 + 8);
            pv0 = *(const int4*)(vgp + jn);
            pv1 = *(const int4*)(vgp + jn + 8);
            int jg = jn + lane;
            mok = (jg < CTXx) ? mrow[jg - 1] : 0;
        }
        // S^T = K.Q^T from LDS K frags
        f32x16 sf[2];
        #pragma unroll
        for (int i = 0; i < 2; i++)
            #pragma unroll
            for (int j = 0; j < 16; j++) sf[i][j] = 0.f;
        #pragma unroll
        for (int ks = 0; ks < 4; ks++){
            #pragma unroll
            for (int kt = 0; kt < 2; kt++){
                bf16x8 kf = *(const bf16x8*)&Ks[p][kt * 32 + n32][ks * 16 + hb * 8];
                sf[kt] = __builtin_amdgcn_mfma_f32_32x32x16_bf16(kf, qf[ks], sf[kt], 0, 0, 0);
            }
        }
        // exp2 + mask + truncating pack (all in registers)
        // key(kt, reg, hb) = kt*32 + 8*(reg>>2) + 4*hb + (reg&3)
        unsigned mlo = (unsigned)(bal >> (4 * hb));
        unsigned mhi = (unsigned)(bal >> (32 + 4 * hb));
        unsigned pg[8][2];
        #pragma unroll
        for (int kt = 0; kt < 2; kt++){
            unsigned mm = kt ? mhi : mlo;
            #pragma unroll
            for (int g4 = 0; g4 < 4; g4++){
                float pr[4];
                #pragma unroll
                for (int tt = 0; tt < 4; tt++){
                    float e = __builtin_amdgcn_exp2f(sf[kt][g4 * 4 + tt]);
                    pr[tt] = ((mm >> (8 * g4 + tt)) & 1u) ? e : 0.f;
                }
                pg[kt * 4 + g4][0] = pack_trunc(pr[0], pr[1]);
                pg[kt * 4 + g4][1] = pack_trunc(pr[2], pr[3]);
            }
        }
        // PV + L: pa lane-local (V pre-permuted); lacc rows align with oacc rows
        #pragma unroll
        for (int s = 0; s < 4; s++){
            bf16x8 pa = __builtin_bit_cast(bf16x8,
                (u32x4){pg[2 * s][0], pg[2 * s][1], pg[2 * s + 1][0], pg[2 * s + 1][1]});
            lacc = __builtin_amdgcn_mfma_f32_32x32x16_bf16(pa, ones, lacc, 0, 0, 0);
            #pragma unroll
            for (int nt = 0; nt < 2; nt++){
                bf16x8 vf = *(const bf16x8*)&Vt[p][nt * 32 + n32][s * 16 + hb * 8];
                oacc[nt] = __builtin_amdgcn_mfma_f32_32x32x16_bf16(pa, vf, oacc[nt], 0, 0, 0);
            }
        }
        p ^= 1;
    }
    // store unnormalized partial O (bf16) + partial L (fp32)
    short* opb = obp + (size_t)half * 8192 * 512;
    float* lpb = lp  + (size_t)half * 65536;
    #pragma unroll
    for (int r = 0; r < 16; r++){
        int hr = (r & 3) + 8 * (r >> 2) + 4 * hb;
        int grow = i0 + (hr & 15);
        int ghead = 2 * w + (hr >> 4);
        short* op = opb + ((size_t)(b * Nx + grow)) * 512 + ghead * 64 + n32;
        op[0]  = f2bs(oacc[0][r]);
        op[32] = f2bs(oacc[1][r]);
        if (n32 == 0) lpb[(size_t)(b * Nx + grow) * 8 + ghead] = lacc[r];
    }
}

// ---------------- reduce: ob = (O0 + O1) / (L0 + L1), bf16 out ----------------
__global__ void __launch_bounds__(256) reduce_kernel(const short* __restrict__ obp,
                                                     const float* __restrict__ lp,
                                                     short* __restrict__ ob){
    int rowg = blockIdx.x;          // b*2048 + row, 0..8191
    int t = threadIdx.x;
    int c = t * 2;                  // 2 dims per thread
    int head = c >> 6;
    float L = lp[(size_t)rowg * 8 + head] + lp[65536 + (size_t)rowg * 8 + head];
    float linv = 1.f / L;
    unsigned u0 = *(const unsigned*)(obp + (size_t)rowg * 512 + c);
    unsigned u1 = *(const unsigned*)(obp + (size_t)8192 * 512 + (size_t)rowg * 512 + c);
    float o0 = (us2f((unsigned short)u0) + us2f((unsigned short)u1)) * linv;
    float o1 = (us2f((unsigned short)(u0 >> 16)) + us2f((unsigned short)(u1 >> 16))) * linv;
    unsigned packed = ((unsigned)(unsigned short)f2bs(o1) << 16) | (unsigned)(unsigned short)f2bs(o0);
    *(unsigned*)(ob + (size_t)rowg * 512 + c) = packed;
}

extern "C" void kernel_launch(void* const* d_in, const int* in_sizes, int n_in,
                              void* d_out, int out_size, void* d_ws, size_t ws_size,
                              hipStream_t stream){
    const float* x     = (const float*)d_in[0];
    const int*   mask  = (const int*)  d_in[1];
    const float* gamma = (const float*)d_in[2];
    const float* Wq    = (const float*)d_in[3];
    const float* Wkv   = (const float*)d_in[4];
    const float* nkv   = (const float*)d_in[5];
    const float* Wout  = (const float*)d_in[6];
    const float* og    = (const float*)d_in[7];
    float* out = (float*)d_out;

    // layout (shorts): [xnb 8MB][obp1 8MB][qb 8MB][kb][vbt][WcatT][WoutT][Lp]
    // aliases: obp = xnb..obp1 (xnb dead after gemm_qkv); ob = qb (qb dead after attn);
    //          zb fp32 16MB = xnb+obp1 (both dead after reduce)
    short* xnb   = (short*)d_ws;                 // 4194304
    short* obp1  = xnb  + (size_t)4194304;       // 4194304 (attn partial half 1)
    short* qb    = obp1 + (size_t)4194304;       // 4194304
    short* kb    = qb   + (size_t)4194304;       // 4*KCAP*64 = 540672
    short* vbt   = kb   + (size_t)540672;        // 540672
    short* WcatT = vbt  + (size_t)540672;        // 327680
    short* WoutT = WcatT + (size_t)327680;       // 262144
    float* Lp    = (float*)(WoutT + 262144);     // 2*65536 floats
    short* obp   = xnb;                          // halves contiguous: [xnb][obp1]
    short* ob    = qb;                           // alias
    float* zb    = (float*)d_ws;                 // alias xnb+obp1

    ln1_prep_kernel<<<2193, 256, 0, stream>>>(x, gamma, xnb, Wq, Wkv, Wout, nkv,
                                              WcatT, WoutT, kb, vbt);
    gemm_mfma<0>  <<<dim3(5, 64), 256, 0, stream>>>(xnb, WcatT, qb, kb, vbt, nullptr);
    attn_kernel   <<<dim3(128, 4, 2), 256, 0, stream>>>(qb, kb, vbt, mask, obp, Lp);
    reduce_kernel <<<8192, 256, 0, stream>>>(obp, Lp, ob);
    gemm_mfma<1>  <<<dim3(4, 64), 256, 0, stream>>>(ob, WoutT, nullptr, nullptr, nullptr, zb);
    ln2_kernel    <<<2048, 256, 0, stream>>>(zb, og, out);
}

// Round 8
// 180.244 us; speedup vs baseline: 1.2969x; 1.2969x over previous
//
#include <hip/hip_runtime.h>

typedef __attribute__((ext_vector_type(8)))  short bf16x8;   // MFMA A/B frag (4 VGPRs)
typedef __attribute__((ext_vector_type(4)))  float f32x4;    // 16x16 C/D frag
typedef __attribute__((ext_vector_type(16))) float f32x16;   // 32x32 C/D frag
typedef __attribute__((ext_vector_type(4)))  unsigned u32x4;

#define Nx 2048
#define CTXx 2049
#define KCAP 2112          // 33 tiles of 64; pad keys stay poison (finite bf16) & masked
#define QSCALE 0.18033688f // 0.125 * log2(e): softmax computed as 2^(S*log2e) = e^S

__device__ __forceinline__ short f2bs(float x){   // float -> bf16 bits (RNE)
    unsigned u = __builtin_bit_cast(unsigned, x);
    u = (u + 0x7fffu + ((u >> 16) & 1u)) >> 16;
    return (short)u;
}
// truncating pack: (hi16 of b)<<16 | (hi16 of a) — 1 v_perm_b32
__device__ __forceinline__ unsigned pack_trunc(float a, float b){
    return __builtin_amdgcn_perm(__builtin_bit_cast(unsigned, b),
                                 __builtin_bit_cast(unsigned, a), 0x07060302u);
}

// ---------------- fused LN1 (blocks 0..2047) + weight prep (2048..2192) ----------------
__global__ void __launch_bounds__(256) ln1_prep_kernel(const float* __restrict__ x,
                                                       const float* __restrict__ g,
                                                       short* __restrict__ xnb,
                                                       const float* __restrict__ Wq,
                                                       const float* __restrict__ Wkv,
                                                       const float* __restrict__ Wout,
                                                       const float* __restrict__ nkv,
                                                       short* __restrict__ WcatT,
                                                       short* __restrict__ WoutT,
                                                       short* __restrict__ kb,
                                                       short* __restrict__ vbt){
    __shared__ float ls[64][65];
    int t = threadIdx.x;
    if (blockIdx.x < 2048){    // ---- LN1: wave per row, fp32 -> bf16 ----
        int w = t >> 6, lane = t & 63;
        size_t row = (size_t)blockIdx.x * 4 + w;
        const float* xr = x + row * 512 + lane * 8;
        float4 a = *(const float4*)xr;
        float4 b = *(const float4*)(xr + 4);
        float s = a.x + a.y + a.z + a.w + b.x + b.y + b.z + b.w;
        float q = a.x*a.x + a.y*a.y + a.z*a.z + a.w*a.w
                + b.x*b.x + b.y*b.y + b.z*b.z + b.w*b.w;
        #pragma unroll
        for (int m = 1; m < 64; m <<= 1){ s += __shfl_xor(s, m, 64); q += __shfl_xor(q, m, 64); }
        float mu  = s * (1.f / 512.f);
        float var = fmaxf(q * (1.f / 512.f) - mu * mu, 0.f);
        float r   = rsqrtf(var + 1e-5f);
        const float* gr = g + lane * 8;
        float4 g0 = *(const float4*)gr;
        float4 g1 = *(const float4*)(gr + 4);
        bf16x8 o;
        o[0] = f2bs((a.x - mu) * r * g0.x); o[1] = f2bs((a.y - mu) * r * g0.y);
        o[2] = f2bs((a.z - mu) * r * g0.z); o[3] = f2bs((a.w - mu) * r * g0.w);
        o[4] = f2bs((b.x - mu) * r * g1.x); o[5] = f2bs((b.y - mu) * r * g1.y);
        o[6] = f2bs((b.z - mu) * r * g1.z); o[7] = f2bs((b.w - mu) * r * g1.w);
        *(bf16x8*)(xnb + row * 512 + lane * 8) = o;
        return;
    }
    int bid = blockIdx.x - 2048;
    if (bid == 144){   // null K/V row (key 0, all batches)
        int b = t >> 6, d = t & 63;
        kb[((size_t)b * KCAP) * 64 + d] = f2bs(nkv[d]);
        vbt[((size_t)b * 64 + d) * KCAP + 0] = f2bs(nkv[64 + d]);
        return;
    }
    // ---- LDS-tiled transpose: 0..79 WcatT (640x512), 80..143 WoutT (512x512) ----
    bool isOut = (bid >= 80);
    int b2 = isOut ? bid - 80 : bid;
    int ntile = isOut ? (b2 & 7) : (b2 % 10);
    int ktile = isOut ? (b2 >> 3) : (b2 / 10);
    int n0 = ntile * 64, k0 = ktile * 64;
    #pragma unroll
    for (int rr = 0; rr < 64; rr += 16){   // coalesced float4 reads of W[k][n]
        int r = rr + (t >> 4), c = (t & 15) * 4;
        float4 v;
        if (isOut)            v = *(const float4*)(Wout + (size_t)(k0 + r) * 512 + n0 + c);
        else if (n0 < 512)    v = *(const float4*)(Wq   + (size_t)(k0 + r) * 512 + n0 + c);
        else                  v = *(const float4*)(Wkv  + (size_t)(k0 + r) * 128 + (n0 - 512) + c);
        ls[c + 0][r] = v.x; ls[c + 1][r] = v.y; ls[c + 2][r] = v.z; ls[c + 3][r] = v.w;
    }
    __syncthreads();
    int rn = t >> 2, kc = (t & 3) * 16;    // coalesced 32B bf16 writes of W^T[n][k]
    short tmp[16];
    #pragma unroll
    for (int j = 0; j < 16; j++) tmp[j] = f2bs(ls[rn][kc + j]);
    short* dst = (isOut ? WoutT : WcatT) + (size_t)(n0 + rn) * 512 + k0 + kc;
    *(int4*)dst       = *(int4*)&tmp[0];
    *(int4*)(dst + 8) = *(int4*)&tmp[8];
}

// ---------------- LN2: fp32 in -> fp32 out, wave per row ----------------
__global__ void __launch_bounds__(256) ln2_kernel(const float* __restrict__ z,
                                                  const float* __restrict__ g,
                                                  float* __restrict__ out){
    int w = threadIdx.x >> 6, lane = threadIdx.x & 63;
    size_t row = (size_t)blockIdx.x * 4 + w;
    const float* xr = z + row * 512 + lane * 8;
    float4 a = *(const float4*)xr;
    float4 b = *(const float4*)(xr + 4);
    float s = a.x + a.y + a.z + a.w + b.x + b.y + b.z + b.w;
    float q = a.x*a.x + a.y*a.y + a.z*a.z + a.w*a.w
            + b.x*b.x + b.y*b.y + b.z*b.z + b.w*b.w;
    #pragma unroll
    for (int m = 1; m < 64; m <<= 1){ s += __shfl_xor(s, m, 64); q += __shfl_xor(q, m, 64); }
    float mu  = s * (1.f / 512.f);
    float var = fmaxf(q * (1.f / 512.f) - mu * mu, 0.f);
    float r   = rsqrtf(var + 1e-5f);
    const float* gr = g + lane * 8;
    float4 g0 = *(const float4*)gr;
    float4 g1 = *(const float4*)(gr + 4);
    float4 o0, o1;
    o0.x = (a.x - mu) * r * g0.x; o0.y = (a.y - mu) * r * g0.y;
    o0.z = (a.z - mu) * r * g0.z; o0.w = (a.w - mu) * r * g0.w;
    o1.x = (b.x - mu) * r * g1.x; o1.y = (b.y - mu) * r * g1.y;
    o1.z = (b.z - mu) * r * g1.z; o1.w = (b.w - mu) * r * g1.w;
    float* op = out + row * 512 + lane * 8;
    *(float4*)op = o0; *(float4*)(op + 4) = o1;
}

// ---------------- GEMM QKV: 128x160 tile, grid (4,64) = 256 blocks = 1/CU (no tail) ----------------
// C = xn @ [Wq|Wkv] (N=640): q-scale(incl log2e) + K scatter + V^T scatter epilogue (bf16)
__global__ void __launch_bounds__(256, 1) gemm_qkv(const short* __restrict__ A,
                                                   const short* __restrict__ BwT,
                                                   short* __restrict__ qb,
                                                   short* __restrict__ kb,
                                                   short* __restrict__ vbt){
    __shared__ short As[2][128][72];   // [buf][m][k]
    __shared__ short Bs[2][160][72];   // [buf][n][k]
    int t = threadIdx.x;
    int lane = t & 63, w = t >> 6;
    int l16 = lane & 15, quad = lane >> 4;
    int wm = w & 1, wn = w >> 1;
    int row0 = blockIdx.y * 128, col0 = blockIdx.x * 160;
    f32x4 acc[4][5];
    #pragma unroll
    for (int i = 0; i < 4; i++)
        #pragma unroll
        for (int j = 0; j < 5; j++) acc[i][j] = (f32x4){0.f, 0.f, 0.f, 0.f};
    int ar = t >> 1, ak = (t & 1) * 32;
    const short* ap = A + (size_t)(row0 + ar) * 512 + ak;
    int4 a0 = *(const int4*)(ap);      int4 a1 = *(const int4*)(ap + 8);
    int4 a2 = *(const int4*)(ap + 16); int4 a3 = *(const int4*)(ap + 24);
    // B staging: 160 rows x 64 k = 1280 int4, 5 per thread, coalesced (idx = pass*256 + t)
    int4 pb[5];
    int brow[5], bseg[5];
    #pragma unroll
    for (int ps = 0; ps < 5; ps++){
        int idx = ps * 256 + t;
        brow[ps] = idx >> 3; bseg[ps] = (idx & 7) * 8;
        pb[ps] = *(const int4*)(BwT + (size_t)(col0 + brow[ps]) * 512 + bseg[ps]);
    }
    int p = 0;
    for (int k0 = 0; k0 < 512; k0 += 64){
        *(int4*)&As[p][ar][ak]      = a0;
        *(int4*)&As[p][ar][ak + 8]  = a1;
        *(int4*)&As[p][ar][ak + 16] = a2;
        *(int4*)&As[p][ar][ak + 24] = a3;
        #pragma unroll
        for (int ps = 0; ps < 5; ps++)
            *(int4*)&Bs[p][brow[ps]][bseg[ps]] = pb[ps];
        __syncthreads();
        int kn = k0 + 64;
        if (kn < 512){   // prefetch next k-slab while computing this one
            a0 = *(const int4*)(ap + kn);      a1 = *(const int4*)(ap + kn + 8);
            a2 = *(const int4*)(ap + kn + 16); a3 = *(const int4*)(ap + kn + 24);
            #pragma unroll
            for (int ps = 0; ps < 5; ps++)
                pb[ps] = *(const int4*)(BwT + (size_t)(col0 + brow[ps]) * 512 + kn + bseg[ps]);
        }
        #pragma unroll
        for (int ks = 0; ks < 2; ks++){
            bf16x8 af[4], bfr[5];
            #pragma unroll
            for (int mt = 0; mt < 4; mt++)
                af[mt] = *(const bf16x8*)&As[p][wm * 64 + mt * 16 + l16][ks * 32 + quad * 8];
            #pragma unroll
            for (int nt = 0; nt < 5; nt++)
                bfr[nt] = *(const bf16x8*)&Bs[p][wn * 80 + nt * 16 + l16][ks * 32 + quad * 8];
            #pragma unroll
            for (int mt = 0; mt < 4; mt++)
                #pragma unroll
                for (int nt = 0; nt < 5; nt++)
                    acc[mt][nt] = __builtin_amdgcn_mfma_f32_16x16x32_bf16(af[mt], bfr[nt], acc[mt][nt], 0, 0, 0);
        }
        p ^= 1;
    }
    #pragma unroll
    for (int mt = 0; mt < 4; mt++)
        #pragma unroll
        for (int nt = 0; nt < 5; nt++)
            #pragma unroll
            for (int r = 0; r < 4; r++){
                int row = row0 + wm * 64 + mt * 16 + quad * 4 + r;
                int col = col0 + wn * 80 + nt * 16 + l16;
                float v = acc[mt][nt][r];
                int bb = row >> 11, ii = row & 2047;
                if (col < 512){
                    qb[(size_t)row * 512 + col] = f2bs(v * QSCALE);
                } else if (col < 576){
                    kb[((size_t)bb * KCAP + ii + 1) * 64 + (col - 512)] = f2bs(v);
                } else {
                    vbt[((size_t)bb * 64 + (col - 576)) * KCAP + ii + 1] = f2bs(v);
                }
            }
}

// ---------------- GEMM OUT: 128x128 tile, grid (4,64) = 256 blocks, fp32 out ----------------
__global__ void __launch_bounds__(256, 2) gemm_out(const short* __restrict__ A,
                                                   const short* __restrict__ BwT,
                                                   float* __restrict__ C){
    __shared__ short As[2][128][72];
    __shared__ short Bs[2][128][72];
    int t = threadIdx.x;
    int lane = t & 63, w = t >> 6;
    int l16 = lane & 15, quad = lane >> 4;
    int wm = w & 1, wn = w >> 1;
    int row0 = blockIdx.y * 128, col0 = blockIdx.x * 128;
    f32x4 acc[4][4];
    #pragma unroll
    for (int i = 0; i < 4; i++)
        #pragma unroll
        for (int j = 0; j < 4; j++) acc[i][j] = (f32x4){0.f, 0.f, 0.f, 0.f};
    int ar = t >> 1, ak = (t & 1) * 32;
    const short* ap = A   + (size_t)(row0 + ar) * 512 + ak;
    const short* bp = BwT + (size_t)(col0 + ar) * 512 + ak;
    int4 a0 = *(const int4*)(ap);      int4 a1 = *(const int4*)(ap + 8);
    int4 a2 = *(const int4*)(ap + 16); int4 a3 = *(const int4*)(ap + 24);
    int4 b0 = *(const int4*)(bp);      int4 b1 = *(const int4*)(bp + 8);
    int4 b2 = *(const int4*)(bp + 16); int4 b3 = *(const int4*)(bp + 24);
    int p = 0;
    for (int k0 = 0; k0 < 512; k0 += 64){
        *(int4*)&As[p][ar][ak]      = a0;
        *(int4*)&As[p][ar][ak + 8]  = a1;
        *(int4*)&As[p][ar][ak + 16] = a2;
        *(int4*)&As[p][ar][ak + 24] = a3;
        *(int4*)&Bs[p][ar][ak]      = b0;
        *(int4*)&Bs[p][ar][ak + 8]  = b1;
        *(int4*)&Bs[p][ar][ak + 16] = b2;
        *(int4*)&Bs[p][ar][ak + 24] = b3;
        __syncthreads();
        int kn = k0 + 64;
        if (kn < 512){
            a0 = *(const int4*)(ap + kn);      a1 = *(const int4*)(ap + kn + 8);
            a2 = *(const int4*)(ap + kn + 16); a3 = *(const int4*)(ap + kn + 24);
            b0 = *(const int4*)(bp + kn);      b1 = *(const int4*)(bp + kn + 8);
            b2 = *(const int4*)(bp + kn + 16); b3 = *(const int4*)(bp + kn + 24);
        }
        #pragma unroll
        for (int ks = 0; ks < 2; ks++){
            bf16x8 af[4], bfr[4];
            #pragma unroll
            for (int mt = 0; mt < 4; mt++)
                af[mt] = *(const bf16x8*)&As[p][wm * 64 + mt * 16 + l16][ks * 32 + quad * 8];
            #pragma unroll
            for (int nt = 0; nt < 4; nt++)
                bfr[nt] = *(const bf16x8*)&Bs[p][wn * 64 + nt * 16 + l16][ks * 32 + quad * 8];
            #pragma unroll
            for (int mt = 0; mt < 4; mt++)
                #pragma unroll
                for (int nt = 0; nt < 4; nt++)
                    acc[mt][nt] = __builtin_amdgcn_mfma_f32_16x16x32_bf16(af[mt], bfr[nt], acc[mt][nt], 0, 0, 0);
        }
        p ^= 1;
    }
    #pragma unroll
    for (int mt = 0; mt < 4; mt++)
        #pragma unroll
        for (int nt = 0; nt < 4; nt++)
            #pragma unroll
            for (int r = 0; r < 4; r++){
                int row = row0 + wm * 64 + mt * 16 + quad * 4 + r;
                int col = col0 + wn * 64 + nt * 16 + l16;
                C[(size_t)row * 512 + col] = acc[mt][nt][r];
            }
}

// ---------------- MFMA attention v5: NO key-split; K+V LDS dbuf, 1 barrier/tile ----------------
// Grid (128 row-tiles, 4 batches). Block = 16 q-rows x 8 heads; wave = 2 heads.
// S^T = K.Q^T (A=K from LDS, B=Q): exp/mask/pack in registers; P->A via bit2<->bit3-swapped V.
// L via mfma(P, ones) -> same reg index as oacc rows -> reg-local normalize, direct bf16 store.
__global__ void __launch_bounds__(256, 2) attn_kernel(const short* __restrict__ qb,
                                                      const short* __restrict__ kb,
                                                      const short* __restrict__ vbt,
                                                      const int* __restrict__ mask,
                                                      short* __restrict__ ob){
    __shared__ short Ks[2][64][72];   // [buf][key][d]
    __shared__ short Vt[2][64][72];   // [buf][d][key], key cols bit2<->bit3 swapped
    int t = threadIdx.x;
    int lane = t & 63, w = t >> 6;
    int n32 = lane & 31, hb = lane >> 5;
    int b = blockIdx.y, i0 = blockIdx.x * 16;
    int head = 2 * w + (n32 >> 4), row = i0 + (n32 & 15);
    // Q frags (B-operand): B[k=8hb+j][n=n32]
    bf16x8 qf[4];
    {
        const short* qp = qb + ((size_t)(b * Nx + row)) * 512 + head * 64 + hb * 8;
        #pragma unroll
        for (int ks = 0; ks < 4; ks++) qf[ks] = *(const bf16x8*)(qp + ks * 16);
    }
    bf16x8 ones;
    #pragma unroll
    for (int j = 0; j < 8; j++) ones[j] = (short)0x3F80;   // bf16 1.0
    f32x16 oacc[2], lacc;
    #pragma unroll
    for (int j = 0; j < 16; j++){ oacc[0][j] = 0.f; oacc[1][j] = 0.f; lacc[j] = 0.f; }

    int skey = t >> 2, sd = (t & 3) * 16;   // K staging: 64 keys x 64 d
    int vd   = t >> 2, vk = (t & 3) * 16;   // V staging: 64 d x 64 keys
    const short* kgp = kb  + (size_t)b * KCAP * 64 + skey * 64 + sd;
    const short* vgp = vbt + ((size_t)b * 64 + vd) * KCAP + vk;
    const int* mrow = mask + b * Nx;

    // prefetch tile 0
    int4 pk0 = *(const int4*)(kgp);
    int4 pk1 = *(const int4*)(kgp + 8);
    int4 pv0 = *(const int4*)(vgp);
    int4 pv1 = *(const int4*)(vgp + 8);
    int mok = (lane == 0) ? 1 : ((lane < CTXx) ? mrow[lane - 1] : 0);

    int p = 0;
    for (int jt = 0; jt < 33; ++jt){
        *(int4*)&Ks[p][skey][sd]     = pk0;
        *(int4*)&Ks[p][skey][sd + 8] = pk1;
        // bit2<->bit3 key permutation == swap middle dwords of the two int4s
        *(int4*)&Vt[p][vd][vk]       = make_int4(pv0.x, pv0.y, pv1.x, pv1.y);
        *(int4*)&Vt[p][vd][vk + 8]   = make_int4(pv0.z, pv0.w, pv1.z, pv1.w);
        unsigned long long bal = __ballot(mok != 0);
        __syncthreads();
        int jn = (jt + 1) * 64;
        if (jt + 1 < 33){   // prefetch next tile into regs (hides under compute)
            pk0 = *(const int4*)(kgp + (size_t)jn * 64);
            pk1 = *(const int4*)(kgp + (size_t)jn * 64 + 8);
            pv0 = *(const int4*)(vgp + jn);
            pv1 = *(const int4*)(vgp + jn + 8);
            int jg = jn + lane;
            mok = (jg < CTXx) ? mrow[jg - 1] : 0;
        }
        // S^T = K.Q^T from LDS K frags
        f32x16 sf[2];
        #pragma unroll
        for (int i = 0; i < 2; i++)
            #pragma unroll
            for (int j = 0; j < 16; j++) sf[i][j] = 0.f;
        #pragma unroll
        for (int ks = 0; ks < 4; ks++){
            #pragma unroll
            for (int kt = 0; kt < 2; kt++){
                bf16x8 kf = *(const bf16x8*)&Ks[p][kt * 32 + n32][ks * 16 + hb * 8];
                sf[kt] = __builtin_amdgcn_mfma_f32_32x32x16_bf16(kf, qf[ks], sf[kt], 0, 0, 0);
            }
        }
        // exp2 + mask + truncating pack (all in registers)
        // key(kt, reg, hb) = kt*32 + 8*(reg>>2) + 4*hb + (reg&3)
        unsigned mlo = (unsigned)(bal >> (4 * hb));
        unsigned mhi = (unsigned)(bal >> (32 + 4 * hb));
        unsigned pg[8][2];
        #pragma unroll
        for (int kt = 0; kt < 2; kt++){
            unsigned mm = kt ? mhi : mlo;
            #pragma unroll
            for (int g4 = 0; g4 < 4; g4++){
                float pr[4];
                #pragma unroll
                for (int tt = 0; tt < 4; tt++){
                    float e = __builtin_amdgcn_exp2f(sf[kt][g4 * 4 + tt]);
                    pr[tt] = ((mm >> (8 * g4 + tt)) & 1u) ? e : 0.f;
                }
                pg[kt * 4 + g4][0] = pack_trunc(pr[0], pr[1]);
                pg[kt * 4 + g4][1] = pack_trunc(pr[2], pr[3]);
            }
        }
        // PV + L: pa lane-local (V pre-permuted); lacc rows align with oacc rows
        #pragma unroll
        for (int s = 0; s < 4; s++){
            bf16x8 pa = __builtin_bit_cast(bf16x8,
                (u32x4){pg[2 * s][0], pg[2 * s][1], pg[2 * s + 1][0], pg[2 * s + 1][1]});
            lacc = __builtin_amdgcn_mfma_f32_32x32x16_bf16(pa, ones, lacc, 0, 0, 0);
            #pragma unroll
            for (int nt = 0; nt < 2; nt++){
                bf16x8 vf = *(const bf16x8*)&Vt[p][nt * 32 + n32][s * 16 + hb * 8];
                oacc[nt] = __builtin_amdgcn_mfma_f32_32x32x16_bf16(pa, vf, oacc[nt], 0, 0, 0);
            }
        }
        p ^= 1;
    }
    // normalize + store: reg r of lacc holds L for the same (head,row) as reg r of oacc
    #pragma unroll
    for (int r = 0; r < 16; r++){
        float linv = 1.f / lacc[r];
        int hr = (r & 3) + 8 * (r >> 2) + 4 * hb;
        int grow = i0 + (hr & 15);
        int ghead = 2 * w + (hr >> 4);
        short* op = ob + ((size_t)(b * Nx + grow)) * 512 + ghead * 64 + n32;
        op[0]  = f2bs(oacc[0][r] * linv);
        op[32] = f2bs(oacc[1][r] * linv);
    }
}

extern "C" void kernel_launch(void* const* d_in, const int* in_sizes, int n_in,
                              void* d_out, int out_size, void* d_ws, size_t ws_size,
                              hipStream_t stream){
    const float* x     = (const float*)d_in[0];
    const int*   mask  = (const int*)  d_in[1];
    const float* gamma = (const float*)d_in[2];
    const float* Wq    = (const float*)d_in[3];
    const float* Wkv   = (const float*)d_in[4];
    const float* nkv   = (const float*)d_in[5];
    const float* Wout  = (const float*)d_in[6];
    const float* og    = (const float*)d_in[7];
    float* out = (float*)d_out;

    short* xnb   = (short*)d_ws;                 // 4194304
    short* qb    = xnb + (size_t)4194304;        // 4194304
    short* kb    = qb  + (size_t)4194304;        // 4*KCAP*64 = 540672
    short* vbt   = kb  + (size_t)540672;         // 540672
    short* ob    = vbt + (size_t)540672;         // 4194304
    short* WcatT = ob  + (size_t)4194304;        // 327680
    short* WoutT = WcatT + (size_t)327680;       // 262144
    float* zb    = (float*)d_ws;                 // aliases xnb+qb (both dead by gemm_out)

    ln1_prep_kernel<<<2193, 256, 0, stream>>>(x, gamma, xnb, Wq, Wkv, Wout, nkv,
                                              WcatT, WoutT, kb, vbt);
    gemm_qkv    <<<dim3(4, 64), 256, 0, stream>>>(xnb, WcatT, qb, kb, vbt);
    attn_kernel <<<dim3(128, 4), 256, 0, stream>>>(qb, kb, vbt, mask, ob);
    gemm_out    <<<dim3(4, 64), 256, 0, stream>>>(ob, WoutT, zb);
    ln2_kernel  <<<2048, 256, 0, stream>>>(zb, og, out);
}